// Round 1
// baseline (463.766 us; speedup 1.0000x reference)
//
#include <hip/hip_runtime.h>
#include <math.h>

// Problem constants (from reference)
#define N0c     292864
#define N1c     11264
#define Bc      1024
#define F_INc   128
#define HIDc    256
#define OUTc    47
#define E0c     281600
#define E1c     10240
#define H_HITc  146432   // == N0 - H_HIT (miss count) as well
#define N_CACHEc 50000
#define C_FEATc 200000
#define Pc      2048

// ---------------------------------------------------------------------------
// map[n] = row index into feat_cache (if < C_FEAT) or C_FEAT + row into x
__global__ void map_kernel(const int* __restrict__ hit_pos, const int* __restrict__ hit_idx,
                           const int* __restrict__ miss_pos, int* __restrict__ map) {
  int i = blockIdx.x * 256 + threadIdx.x;
  if (i < H_HITc) {
    map[hit_pos[i]]  = hit_idx[i];
    map[miss_pos[i]] = C_FEATc + i;
  }
}

__global__ void deg_kernel(const int* __restrict__ dst, int* __restrict__ deg, int E) {
  int e = blockIdx.x * 256 + threadIdx.x;
  if (e < E) atomicAdd(&deg[dst[e]], 1);
}

// single-block exclusive scan: off[0]=0, off[i+1]=sum(deg[0..i])
__global__ void scan_kernel(const int* __restrict__ deg, int* __restrict__ off, int n) {
  __shared__ int buf[1024];
  __shared__ int carryS;
  int tid = threadIdx.x;
  if (tid == 0) { carryS = 0; off[0] = 0; }
  __syncthreads();
  for (int base = 0; base < n; base += 1024) {
    int i = base + tid;
    int v = (i < n) ? deg[i] : 0;
    buf[tid] = v;
    __syncthreads();
    for (int ofs = 1; ofs < 1024; ofs <<= 1) {
      int t = (tid >= ofs) ? buf[tid - ofs] : 0;
      __syncthreads();
      buf[tid] += t;
      __syncthreads();
    }
    int c = carryS;
    if (i < n) off[i + 1] = c + buf[tid];
    __syncthreads();
    if (tid == 0) carryS = c + buf[1023];
    __syncthreads();
  }
}

__global__ void copy_kernel(const int* __restrict__ a, int* __restrict__ b, int n) {
  int i = blockIdx.x * 256 + threadIdx.x;
  if (i < n) b[i] = a[i];
}

__global__ void scatter_kernel(const int* __restrict__ src, const int* __restrict__ dst,
                               int* __restrict__ cursor, int* __restrict__ esrc, int E) {
  int e = blockIdx.x * 256 + threadIdx.x;
  if (e < E) {
    int p = atomicAdd(&cursor[dst[e]], 1);
    esrc[p] = src[e];
  }
}

// Conv1 aggregation: one block (128 threads) per dst node; mean of neighbor rows.
__global__ void agg1_kernel(const int* __restrict__ off, const int* __restrict__ esrc,
                            const int* __restrict__ map, const float* __restrict__ feat_cache,
                            const float* __restrict__ x, float* __restrict__ mean) {
  int d = blockIdx.x;
  int t = threadIdx.x;  // 0..127
  int s = off[d], e = off[d + 1];
  float acc = 0.f;
  for (int i = s; i < e; ++i) {
    int m = map[esrc[i]];
    const float* row = (m < C_FEATc) ? (feat_cache + (size_t)m * F_INc)
                                     : (x + (size_t)(m - C_FEATc) * F_INc);
    acc += row[t];
  }
  mean[(size_t)d * F_INc + t] = acc / fmaxf((float)(e - s), 1.f);
}

// h1 = relu(mean @ W0l + b0 + hdst @ W0r)   (N1 x 256)
#define ROWS1 16
__global__ __launch_bounds__(256) void gemm1_kernel(
    const float* __restrict__ mean, const int* __restrict__ map,
    const float* __restrict__ feat_cache, const float* __restrict__ x,
    const float* __restrict__ W0l, const float* __restrict__ b0,
    const float* __restrict__ W0r, float* __restrict__ h1) {
  __shared__ float lin[ROWS1][256];  // [r][0..127]=mean row, [r][128..255]=hdst row
  int g0 = blockIdx.x * ROWS1;
  int tid = threadIdx.x;
  for (int idx = tid; idx < ROWS1 * 128; idx += 256) {
    int r = idx >> 7, k = idx & 127;
    lin[r][k] = mean[(size_t)(g0 + r) * F_INc + k];
  }
  for (int idx = tid; idx < ROWS1 * 128; idx += 256) {
    int r = idx >> 7, k = idx & 127;
    int m = map[g0 + r];
    const float* row = (m < C_FEATc) ? (feat_cache + (size_t)m * F_INc)
                                     : (x + (size_t)(m - C_FEATc) * F_INc);
    lin[r][128 + k] = row[k];
  }
  __syncthreads();
  int col = tid;  // 0..255
  float acc[ROWS1];
#pragma unroll
  for (int r = 0; r < ROWS1; ++r) acc[r] = 0.f;
  for (int k = 0; k < 128; ++k) {
    float wl = W0l[k * 256 + col];
#pragma unroll
    for (int r = 0; r < ROWS1; ++r) acc[r] += lin[r][k] * wl;
  }
  for (int k = 0; k < 128; ++k) {
    float wr = W0r[k * 256 + col];
#pragma unroll
    for (int r = 0; r < ROWS1; ++r) acc[r] += lin[r][128 + k] * wr;
  }
  float b = b0[col];
  for (int r = 0; r < ROWS1; ++r) {
    float v = acc[r] + b;
    h1[(size_t)(g0 + r) * HIDc + col] = v > 0.f ? v : 0.f;
  }
}

// last-wins winner per cache slot (np duplicate-assignment semantics)
__global__ void push_win_kernel(const int* __restrict__ push_gid, const int* __restrict__ table,
                                int* __restrict__ win) {
  int i = blockIdx.x * 256 + threadIdx.x;
  if (i < Pc) atomicMax(&win[table[push_gid[i]]], i);
}

__global__ void pull_win_kernel(const int* __restrict__ pull_bid, int* __restrict__ pwin) {
  int i = blockIdx.x * 256 + threadIdx.x;
  if (i < Pc) atomicMax(&pwin[pull_bid[i]], i);
}

// Stage pulled rows (only for winning pulls): value comes from pushed h1 row (if the
// slot was pushed) or from the pristine emb_cache. Reads pre-pull h1.
__global__ void pull_gather_kernel(const int* __restrict__ pull_bid, const int* __restrict__ pull_gid,
                                   const int* __restrict__ table, const int* __restrict__ win,
                                   const int* __restrict__ pwin, const int* __restrict__ push_bid,
                                   const float* __restrict__ h1, const float* __restrict__ emb_cache,
                                   float* __restrict__ pulled) {
  int i = blockIdx.x;
  int t = threadIdx.x;  // 256
  if (pwin[pull_bid[i]] != i) return;
  int slot = table[pull_gid[i]];
  int j = win[slot];
  const float* src = (j >= 0) ? (h1 + (size_t)push_bid[j] * HIDc)
                              : (emb_cache + (size_t)slot * HIDc);
  pulled[(size_t)i * HIDc + t] = src[t];
}

__global__ void pull_apply_kernel(const int* __restrict__ pull_bid, const int* __restrict__ pwin,
                                  const float* __restrict__ pulled, float* __restrict__ h1) {
  int i = blockIdx.x;
  int t = threadIdx.x;
  if (pwin[pull_bid[i]] != i) return;
  h1[(size_t)pull_bid[i] * HIDc + t] = pulled[(size_t)i * HIDc + t];
}

// Conv2 aggregation: one block (256 threads) per dst in [0,B)
__global__ void agg2_kernel(const int* __restrict__ off, const int* __restrict__ esrc,
                            const float* __restrict__ h1, float* __restrict__ mean2) {
  int d = blockIdx.x;
  int t = threadIdx.x;
  int s = off[d], e = off[d + 1];
  float acc = 0.f;
  for (int i = s; i < e; ++i) acc += h1[(size_t)esrc[i] * HIDc + t];
  mean2[(size_t)d * HIDc + t] = acc / fmaxf((float)(e - s), 1.f);
}

// out[row] = log_softmax(mean2 @ W1l + b1 + h1row @ W1r); one wave per row.
__global__ __launch_bounds__(64) void gemm2_lsm_kernel(
    const float* __restrict__ mean2, const float* __restrict__ h1,
    const float* __restrict__ W1l, const float* __restrict__ b1,
    const float* __restrict__ W1r, float* __restrict__ out) {
  __shared__ float lin[512];
  int row = blockIdx.x;
  int tid = threadIdx.x;  // 64
  for (int i = tid; i < 256; i += 64) lin[i] = mean2[(size_t)row * HIDc + i];
  for (int i = tid; i < 256; i += 64) lin[256 + i] = h1[(size_t)row * HIDc + i];
  __syncthreads();
  float acc = 0.f;
  if (tid < OUTc) {
    for (int k = 0; k < 256; ++k) acc += lin[k] * W1l[k * OUTc + tid];
    for (int k = 0; k < 256; ++k) acc += lin[256 + k] * W1r[k * OUTc + tid];
    acc += b1[tid];
  }
  float v = (tid < OUTc) ? acc : -INFINITY;
  float m = v;
  for (int o = 32; o > 0; o >>= 1) m = fmaxf(m, __shfl_xor(m, o));
  float ex = (tid < OUTc) ? expf(v - m) : 0.f;
  float s = ex;
  for (int o = 32; o > 0; o >>= 1) s += __shfl_xor(s, o);
  if (tid < OUTc) out[(size_t)row * OUTc + tid] = v - m - logf(s);
}

// ---------------------------------------------------------------------------
extern "C" void kernel_launch(void* const* d_in, const int* in_sizes, int n_in,
                              void* d_out, int out_size, void* d_ws, size_t ws_size,
                              hipStream_t stream) {
  const float* x          = (const float*)d_in[0];
  const float* feat_cache = (const float*)d_in[1];
  const float* emb_cache  = (const float*)d_in[2];
  const int* hit_idx      = (const int*)d_in[3];
  const int* hit_pos      = (const int*)d_in[4];
  const int* miss_pos     = (const int*)d_in[5];
  const int* e0           = (const int*)d_in[6];   // [src E0][dst E0]
  const int* e1           = (const int*)d_in[7];   // [src E1][dst E1]
  const int* table        = (const int*)d_in[8];
  const int* push_bid     = (const int*)d_in[9];
  const int* push_gid     = (const int*)d_in[10];
  const int* pull_bid     = (const int*)d_in[11];
  const int* pull_gid     = (const int*)d_in[12];
  const float* W0l        = (const float*)d_in[13];
  const float* b0         = (const float*)d_in[14];
  const float* W0r        = (const float*)d_in[15];
  const float* W1l        = (const float*)d_in[16];
  const float* b1         = (const float*)d_in[17];
  const float* W1r        = (const float*)d_in[18];
  float* out = (float*)d_out;

  char* p = (char*)d_ws;
  size_t ob = 0;
  auto take = [&](size_t bytes) -> void* {
    void* r = p + ob;
    ob += (bytes + 255) & ~(size_t)255;
    return r;
  };
  int* MAP     = (int*)take((size_t)N0c * 4);
  int* OFF0    = (int*)take((size_t)(N1c + 1) * 4);
  int* CUR0    = (int*)take((size_t)N1c * 4);           // deg0, then cursor0
  int* ESRC0   = (int*)take((size_t)E0c * 4);
  float* MEAN1 = (float*)take((size_t)N1c * F_INc * 4);
  float* H1    = (float*)take((size_t)N1c * HIDc * 4);
  int* WIN     = (int*)take((size_t)N_CACHEc * 4);
  int* PWIN    = (int*)take((size_t)N1c * 4);
  float* PULLED= (float*)take((size_t)Pc * HIDc * 4);
  int* OFF1    = (int*)take((size_t)(Bc + 1) * 4);
  int* CUR1    = (int*)take((size_t)Bc * 4);            // deg1, then cursor1
  int* ESRC1   = (int*)take((size_t)E1c * 4);
  float* MEAN2 = (float*)take((size_t)Bc * HIDc * 4);

  // init scratch that needs defined values (ws is poisoned each launch)
  hipMemsetAsync(CUR0, 0,    (size_t)N1c * 4, stream);
  hipMemsetAsync(CUR1, 0,    (size_t)Bc * 4, stream);
  hipMemsetAsync(WIN,  0xFF, (size_t)N_CACHEc * 4, stream);
  hipMemsetAsync(PWIN, 0xFF, (size_t)N1c * 4, stream);

  // h indirection map
  map_kernel<<<(H_HITc + 255) / 256, 256, 0, stream>>>(hit_pos, hit_idx, miss_pos, MAP);

  // CSR for edge_index0
  deg_kernel<<<(E0c + 255) / 256, 256, 0, stream>>>(e0 + E0c, CUR0, E0c);
  scan_kernel<<<1, 1024, 0, stream>>>(CUR0, OFF0, N1c);
  copy_kernel<<<(N1c + 255) / 256, 256, 0, stream>>>(OFF0, CUR0, N1c);
  scatter_kernel<<<(E0c + 255) / 256, 256, 0, stream>>>(e0, e0 + E0c, CUR0, ESRC0, E0c);

  // conv1: mean aggregation + GEMM + relu
  agg1_kernel<<<N1c, 128, 0, stream>>>(OFF0, ESRC0, MAP, feat_cache, x, MEAN1);
  gemm1_kernel<<<N1c / ROWS1, 256, 0, stream>>>(MEAN1, MAP, feat_cache, x, W0l, b0, W0r, H1);

  // push/pull with last-wins duplicate semantics (emb_cache untouched)
  push_win_kernel<<<(Pc + 255) / 256, 256, 0, stream>>>(push_gid, table, WIN);
  pull_win_kernel<<<(Pc + 255) / 256, 256, 0, stream>>>(pull_bid, PWIN);
  pull_gather_kernel<<<Pc, HIDc, 0, stream>>>(pull_bid, pull_gid, table, WIN, PWIN,
                                              push_bid, H1, emb_cache, PULLED);
  pull_apply_kernel<<<Pc, HIDc, 0, stream>>>(pull_bid, PWIN, PULLED, H1);

  // CSR for edge_index1
  deg_kernel<<<(E1c + 255) / 256, 256, 0, stream>>>(e1 + E1c, CUR1, E1c);
  scan_kernel<<<1, 1024, 0, stream>>>(CUR1, OFF1, Bc);
  copy_kernel<<<(Bc + 255) / 256, 256, 0, stream>>>(OFF1, CUR1, Bc);
  scatter_kernel<<<(E1c + 255) / 256, 256, 0, stream>>>(e1, e1 + E1c, CUR1, ESRC1, E1c);

  // conv2 + log_softmax
  agg2_kernel<<<Bc, HIDc, 0, stream>>>(OFF1, ESRC1, H1, MEAN2);
  gemm2_lsm_kernel<<<Bc, 64, 0, stream>>>(MEAN2, H1, W1l, b1, W1r, out);
}

// Round 2
// 362.261 us; speedup vs baseline: 1.2802x; 1.2802x over previous
//
#include <hip/hip_runtime.h>
#include <math.h>

// Problem constants (from reference)
#define N0c     292864
#define N1c     11264
#define Bc      1024
#define F_INc   128
#define HIDc    256
#define OUTc    47
#define E0c     281600
#define E1c     10240
#define H_HITc  146432
#define N_CACHEc 50000
#define C_FEATc 200000
#define Pc      2048

// ---------------------------------------------------------------------------
// prep: build map (h indirection) + init all scratch (replaces 4 memsets)
__global__ void prep_kernel(const int* __restrict__ hit_pos, const int* __restrict__ hit_idx,
                            const int* __restrict__ miss_pos, int* __restrict__ map,
                            int* __restrict__ cur0, int* __restrict__ pwin,
                            int* __restrict__ cur1, int* __restrict__ win) {
  int i = blockIdx.x * 256 + threadIdx.x;
  if (i < H_HITc) {
    map[hit_pos[i]]  = hit_idx[i];
    map[miss_pos[i]] = C_FEATc + i;
  }
  if (i < N1c) { cur0[i] = 0; pwin[i] = -1; }
  if (i < Bc)  cur1[i] = 0;
  if (i < N_CACHEc) win[i] = -1;
}

// degree count for both graphs in one dispatch (into cur0/cur1, reused as deg)
__global__ void deg_both_kernel(const int* __restrict__ e0, const int* __restrict__ e1,
                                int* __restrict__ deg0, int* __restrict__ deg1) {
  int i = blockIdx.x * 256 + threadIdx.x;
  if (i < E0c) {
    atomicAdd(&deg0[e0[E0c + i]], 1);
  } else if (i < E0c + E1c) {
    int j = i - E0c;
    atomicAdd(&deg1[e1[E1c + j]], 1);
  }
}

// block-wide exclusive scan: reads deg (aliased with cur), writes off[0..n] and cur[0..n-1]
__device__ void scan_block(const int* __restrict__ deg, int* __restrict__ off,
                           int* __restrict__ cur, int n) {
  __shared__ int wsum[16];
  int tid = threadIdx.x;
  int lane = tid & 63, wid = tid >> 6;
  int ITEMS = (n + 1023) >> 10;   // <= 11
  int base = tid * ITEMS;
  int v[12];
  int sum = 0;
  for (int j = 0; j < ITEMS; ++j) {
    int i = base + j;
    v[j] = (i < n) ? deg[i] : 0;
    sum += v[j];
  }
  // inclusive wave scan
  int s = sum;
  for (int o = 1; o < 64; o <<= 1) {
    int t = __shfl_up(s, o);
    if (lane >= o) s += t;
  }
  if (lane == 63) wsum[wid] = s;
  __syncthreads();
  if (tid < 16) {
    int w = wsum[tid];
    for (int o = 1; o < 16; o <<= 1) {
      int t = __shfl_up(w, o);
      if (tid >= o) w += t;
    }
    wsum[tid] = w;  // inclusive wave totals
  }
  __syncthreads();
  int wbase = (wid > 0) ? wsum[wid - 1] : 0;
  int run = wbase + s - sum;     // exclusive prefix for this thread's chunk
  for (int j = 0; j < ITEMS; ++j) {
    int i = base + j;
    if (i < n) { off[i] = run; cur[i] = run; run += v[j]; }
  }
  if (tid == 1023) off[n] = run;  // grand total
}

__global__ __launch_bounds__(1024) void scan_both_kernel(
    int* __restrict__ cur0, int* __restrict__ off0,
    int* __restrict__ cur1, int* __restrict__ off1) {
  if (blockIdx.x == 0) scan_block(cur0, off0, cur0, N1c);
  else                 scan_block(cur1, off1, cur1, Bc);
}

// scatter both graphs; layer-0 sources are map-resolved here (removes map chase in agg1)
__global__ void scatter_both_kernel(const int* __restrict__ e0, const int* __restrict__ e1,
                                    const int* __restrict__ map,
                                    int* __restrict__ cur0, int* __restrict__ esrc0,
                                    int* __restrict__ cur1, int* __restrict__ esrc1) {
  int i = blockIdx.x * 256 + threadIdx.x;
  if (i < E0c) {
    int p = atomicAdd(&cur0[e0[E0c + i]], 1);
    esrc0[p] = map[e0[i]];
  } else if (i < E0c + E1c) {
    int j = i - E0c;
    int p = atomicAdd(&cur1[e1[E1c + j]], 1);
    esrc1[p] = e1[j];
  }
}

// Conv1 aggregation: one block (256 thr = 8 row-slots x 32 lanes) per dst; float4 gathers.
__global__ __launch_bounds__(256) void agg1_kernel(
    const int* __restrict__ off, const int* __restrict__ esrc,
    const float* __restrict__ fc, const float* __restrict__ x,
    float4* __restrict__ mean4) {
  __shared__ float4 sbuf[8][32];
  int d = blockIdx.x;
  int slot = threadIdx.x >> 5, lane = threadIdx.x & 31;
  int s = off[d], e = off[d + 1];
  float4 acc = make_float4(0.f, 0.f, 0.f, 0.f);
  int i = s + slot;
  int m = (i < e) ? esrc[i] : -1;
  while (i < e) {
    int inext = i + 8;
    int mnext = (inext < e) ? esrc[inext] : -1;   // prefetch next index
    const float* row = (m < C_FEATc) ? (fc + (size_t)m * F_INc)
                                     : (x + (size_t)(m - C_FEATc) * F_INc);
    float4 v = ((const float4*)row)[lane];
    acc.x += v.x; acc.y += v.y; acc.z += v.z; acc.w += v.w;
    i = inext; m = mnext;
  }
  sbuf[slot][lane] = acc;
  __syncthreads();
  if (slot < 4) {
    float4 o = sbuf[slot + 4][lane];
    acc.x += o.x; acc.y += o.y; acc.z += o.z; acc.w += o.w;
    sbuf[slot][lane] = acc;
  }
  __syncthreads();
  if (slot < 2) {
    float4 o = sbuf[slot + 2][lane];
    acc.x += o.x; acc.y += o.y; acc.z += o.z; acc.w += o.w;
    sbuf[slot][lane] = acc;
  }
  __syncthreads();
  if (slot == 0) {
    float4 o = sbuf[1][lane];
    acc.x += o.x; acc.y += o.y; acc.z += o.z; acc.w += o.w;
    float inv = 1.f / fmaxf((float)(e - s), 1.f);
    float4 r = make_float4(acc.x * inv, acc.y * inv, acc.z * inv, acc.w * inv);
    mean4[(size_t)d * 32 + lane] = r;
  }
}

// h1 = relu(mean @ W0l + b0 + hdst @ W0r)   (N1 x 256); A-operand via ds_read_b128
#define ROWS1 16
__global__ __launch_bounds__(256) void gemm1_kernel(
    const float4* __restrict__ mean4, const int* __restrict__ map,
    const float* __restrict__ fc, const float* __restrict__ x,
    const float* __restrict__ W0l, const float* __restrict__ b0,
    const float* __restrict__ W0r, float* __restrict__ h1) {
  __shared__ float lin[ROWS1][256];  // [r][0..127]=mean row, [r][128..255]=hdst row
  int g0 = blockIdx.x * ROWS1;
  int tid = threadIdx.x;
  // stage mean rows (float4)
  for (int idx = tid; idx < ROWS1 * 32; idx += 256) {
    int r = idx >> 5, l = idx & 31;
    ((float4*)&lin[r][0])[l] = mean4[(size_t)(g0 + r) * 32 + l];
  }
  // stage hdst rows (gather, float4)
  for (int idx = tid; idx < ROWS1 * 32; idx += 256) {
    int r = idx >> 5, l = idx & 31;
    int m = map[g0 + r];
    const float* row = (m < C_FEATc) ? (fc + (size_t)m * F_INc)
                                     : (x + (size_t)(m - C_FEATc) * F_INc);
    ((float4*)&lin[r][128])[l] = ((const float4*)row)[l];
  }
  __syncthreads();
  int col = tid;  // 0..255
  float acc[ROWS1];
#pragma unroll
  for (int r = 0; r < ROWS1; ++r) acc[r] = 0.f;
  for (int kb = 0; kb < 32; ++kb) {
    float w0 = W0l[(kb * 4 + 0) * 256 + col];
    float w1 = W0l[(kb * 4 + 1) * 256 + col];
    float w2 = W0l[(kb * 4 + 2) * 256 + col];
    float w3 = W0l[(kb * 4 + 3) * 256 + col];
#pragma unroll
    for (int r = 0; r < ROWS1; ++r) {
      float4 a = *(const float4*)&lin[r][kb * 4];
      acc[r] += a.x * w0 + a.y * w1 + a.z * w2 + a.w * w3;
    }
  }
  for (int kb = 0; kb < 32; ++kb) {
    float w0 = W0r[(kb * 4 + 0) * 256 + col];
    float w1 = W0r[(kb * 4 + 1) * 256 + col];
    float w2 = W0r[(kb * 4 + 2) * 256 + col];
    float w3 = W0r[(kb * 4 + 3) * 256 + col];
#pragma unroll
    for (int r = 0; r < ROWS1; ++r) {
      float4 a = *(const float4*)&lin[r][128 + kb * 4];
      acc[r] += a.x * w0 + a.y * w1 + a.z * w2 + a.w * w3;
    }
  }
  float b = b0[col];
#pragma unroll
  for (int r = 0; r < ROWS1; ++r) {
    float v = acc[r] + b;
    h1[(size_t)(g0 + r) * HIDc + col] = v > 0.f ? v : 0.f;
  }
}

// push winners (last-wins per cache slot) + pull winners (last-wins per batch row)
__global__ void win_both_kernel(const int* __restrict__ push_gid, const int* __restrict__ table,
                                int* __restrict__ win,
                                const int* __restrict__ pull_bid, int* __restrict__ pwin) {
  int i = blockIdx.x * 256 + threadIdx.x;
  if (i < Pc) atomicMax(&win[table[push_gid[i]]], i);
  else if (i < 2 * Pc) {
    int j = i - Pc;
    atomicMax(&pwin[pull_bid[j]], j);
  }
}

// Stage pulled rows for winning pulls (reads pre-pull h1 / pristine emb_cache)
__global__ void pull_gather_kernel(const int* __restrict__ pull_bid, const int* __restrict__ pull_gid,
                                   const int* __restrict__ table, const int* __restrict__ win,
                                   const int* __restrict__ pwin, const int* __restrict__ push_bid,
                                   const float* __restrict__ h1, const float* __restrict__ emb_cache,
                                   float* __restrict__ pulled) {
  int i = blockIdx.x;
  int t = threadIdx.x;  // 256
  if (pwin[pull_bid[i]] != i) return;
  int slot = table[pull_gid[i]];
  int j = win[slot];
  const float* src = (j >= 0) ? (h1 + (size_t)push_bid[j] * HIDc)
                              : (emb_cache + (size_t)slot * HIDc);
  pulled[(size_t)i * HIDc + t] = src[t];
}

__global__ void pull_apply_kernel(const int* __restrict__ pull_bid, const int* __restrict__ pwin,
                                  const float* __restrict__ pulled, float* __restrict__ h1) {
  int i = blockIdx.x;
  int t = threadIdx.x;
  if (pwin[pull_bid[i]] != i) return;
  h1[(size_t)pull_bid[i] * HIDc + t] = pulled[(size_t)i * HIDc + t];
}

// Fused conv2: mean-agg + GEMM(K=512 concat) + bias + log_softmax. One block per out row.
__global__ __launch_bounds__(256) void conv2_kernel(
    const int* __restrict__ off, const int* __restrict__ esrc,
    const float* __restrict__ h1,
    const float* __restrict__ W1l, const float* __restrict__ b1,
    const float* __restrict__ W1r, float* __restrict__ out) {
  __shared__ float lin[512];
  __shared__ float partial[64][4];
  int row = blockIdx.x;
  int t = threadIdx.x;  // 256
  int s = off[row], e = off[row + 1];
  float acc = 0.f;
  for (int i = s; i < e; ++i) acc += h1[(size_t)esrc[i] * HIDc + t];
  lin[t] = acc / fmaxf((float)(e - s), 1.f);
  lin[256 + t] = h1[(size_t)row * HIDc + t];
  __syncthreads();
  int col = t >> 2;   // 0..63
  int seg = t & 3;    // k-quarter
  float p = 0.f;
  if (col < OUTc) {
    int k0 = seg * 64;
    for (int k = k0; k < k0 + 64; ++k) p += lin[k] * W1l[k * OUTc + col];
    for (int k = k0; k < k0 + 64; ++k) p += lin[256 + k] * W1r[k * OUTc + col];
  }
  partial[col][seg] = p;
  __syncthreads();
  if (t < 64) {
    float v = partial[t][0] + partial[t][1] + partial[t][2] + partial[t][3];
    if (t < OUTc) v += b1[t];
    float vv = (t < OUTc) ? v : -INFINITY;
    float m = vv;
    for (int o = 32; o > 0; o >>= 1) m = fmaxf(m, __shfl_xor(m, o));
    float ex = (t < OUTc) ? expf(vv - m) : 0.f;
    float sum = ex;
    for (int o = 32; o > 0; o >>= 1) sum += __shfl_xor(sum, o);
    if (t < OUTc) out[(size_t)row * OUTc + t] = vv - m - logf(sum);
  }
}

// ---------------------------------------------------------------------------
extern "C" void kernel_launch(void* const* d_in, const int* in_sizes, int n_in,
                              void* d_out, int out_size, void* d_ws, size_t ws_size,
                              hipStream_t stream) {
  const float* x          = (const float*)d_in[0];
  const float* feat_cache = (const float*)d_in[1];
  const float* emb_cache  = (const float*)d_in[2];
  const int* hit_idx      = (const int*)d_in[3];
  const int* hit_pos      = (const int*)d_in[4];
  const int* miss_pos     = (const int*)d_in[5];
  const int* e0           = (const int*)d_in[6];
  const int* e1           = (const int*)d_in[7];
  const int* table        = (const int*)d_in[8];
  const int* push_bid     = (const int*)d_in[9];
  const int* push_gid     = (const int*)d_in[10];
  const int* pull_bid     = (const int*)d_in[11];
  const int* pull_gid     = (const int*)d_in[12];
  const float* W0l        = (const float*)d_in[13];
  const float* b0         = (const float*)d_in[14];
  const float* W0r        = (const float*)d_in[15];
  const float* W1l        = (const float*)d_in[16];
  const float* b1         = (const float*)d_in[17];
  const float* W1r        = (const float*)d_in[18];
  float* out = (float*)d_out;

  char* p = (char*)d_ws;
  size_t ob = 0;
  auto take = [&](size_t bytes) -> void* {
    void* r = p + ob;
    ob += (bytes + 255) & ~(size_t)255;
    return r;
  };
  int* MAP     = (int*)take((size_t)N0c * 4);
  int* OFF0    = (int*)take((size_t)(N1c + 1) * 4);
  int* CUR0    = (int*)take((size_t)N1c * 4);           // deg0 -> cursor0
  int* ESRC0   = (int*)take((size_t)E0c * 4);
  float* MEAN1 = (float*)take((size_t)N1c * F_INc * 4);
  float* H1    = (float*)take((size_t)N1c * HIDc * 4);
  int* WIN     = (int*)take((size_t)N_CACHEc * 4);
  int* PWIN    = (int*)take((size_t)N1c * 4);
  float* PULLED= (float*)take((size_t)Pc * HIDc * 4);
  int* OFF1    = (int*)take((size_t)(Bc + 1) * 4);
  int* CUR1    = (int*)take((size_t)Bc * 4);            // deg1 -> cursor1
  int* ESRC1   = (int*)take((size_t)E1c * 4);

  // 1. map + scratch init
  prep_kernel<<<(H_HITc + 255) / 256, 256, 0, stream>>>(hit_pos, hit_idx, miss_pos,
                                                        MAP, CUR0, PWIN, CUR1, WIN);
  // 2. degrees (both graphs)
  deg_both_kernel<<<(E0c + E1c + 255) / 256, 256, 0, stream>>>(e0, e1, CUR0, CUR1);
  // 3. scans (both graphs, shfl-based)
  scan_both_kernel<<<2, 1024, 0, stream>>>(CUR0, OFF0, CUR1, OFF1);
  // 4. scatter (both graphs; layer-0 map-resolved)
  scatter_both_kernel<<<(E0c + E1c + 255) / 256, 256, 0, stream>>>(e0, e1, MAP,
                                                                  CUR0, ESRC0, CUR1, ESRC1);
  // 5. conv1 aggregation
  agg1_kernel<<<N1c, 256, 0, stream>>>(OFF0, ESRC0, feat_cache, x, (float4*)MEAN1);
  // 6. conv1 GEMM + relu
  gemm1_kernel<<<N1c / ROWS1, 256, 0, stream>>>((const float4*)MEAN1, MAP, feat_cache, x,
                                                W0l, b0, W0r, H1);
  // 7. push/pull winners
  win_both_kernel<<<(2 * Pc + 255) / 256, 256, 0, stream>>>(push_gid, table, WIN, pull_bid, PWIN);
  // 8-9. pull gather/apply (last-wins, emb_cache untouched)
  pull_gather_kernel<<<Pc, HIDc, 0, stream>>>(pull_bid, pull_gid, table, WIN, PWIN,
                                              push_bid, H1, emb_cache, PULLED);
  pull_apply_kernel<<<Pc, HIDc, 0, stream>>>(pull_bid, PWIN, PULLED, H1);
  // 10. conv2 + log_softmax (fused)
  conv2_kernel<<<Bc, 256, 0, stream>>>(OFF1, ESRC1, H1, W1l, b1, W1r, out);
}

// Round 3
// 353.949 us; speedup vs baseline: 1.3103x; 1.0235x over previous
//
#include <hip/hip_runtime.h>
#include <math.h>

// Problem constants (from reference)
#define N0c     292864
#define N1c     11264
#define Bc      1024
#define F_INc   128
#define HIDc    256
#define OUTc    47
#define E0c     281600
#define E1c     10240
#define H_HITc  146432
#define N_CACHEc 50000
#define C_FEATc 200000
#define Pc      2048

// ---------------------------------------------------------------------------
// prep: build map (h indirection) + init all scratch (no hipMemsetAsync needed)
__global__ void prep_kernel(const int* __restrict__ hit_pos, const int* __restrict__ hit_idx,
                            const int* __restrict__ miss_pos, int* __restrict__ map,
                            int* __restrict__ cur0, int* __restrict__ pwin,
                            int* __restrict__ cur1, int* __restrict__ win,
                            int* __restrict__ src_row) {
  int i = blockIdx.x * 256 + threadIdx.x;
  if (i < H_HITc) {
    map[hit_pos[i]]  = hit_idx[i];
    map[miss_pos[i]] = C_FEATc + i;
  }
  if (i < N1c) { cur0[i] = 0; pwin[i] = -1; src_row[i] = i; }
  if (i < Bc)  cur1[i] = 0;
  if (i < N_CACHEc) win[i] = -1;
}

// degree count for both graphs in one dispatch
__global__ void deg_both_kernel(const int* __restrict__ e0, const int* __restrict__ e1,
                                int* __restrict__ deg0, int* __restrict__ deg1) {
  int i = blockIdx.x * 256 + threadIdx.x;
  if (i < E0c) {
    atomicAdd(&deg0[e0[E0c + i]], 1);
  } else if (i < E0c + E1c) {
    int j = i - E0c;
    atomicAdd(&deg1[e1[E1c + j]], 1);
  }
}

// block-wide exclusive scan (shfl-based), writes off[0..n] and cur[0..n-1]
__device__ void scan_block(const int* __restrict__ deg, int* __restrict__ off,
                           int* __restrict__ cur, int n) {
  __shared__ int wsum[16];
  int tid = threadIdx.x;
  int lane = tid & 63, wid = tid >> 6;
  int ITEMS = (n + 1023) >> 10;
  int base = tid * ITEMS;
  int v[12];
  int sum = 0;
  for (int j = 0; j < ITEMS; ++j) {
    int i = base + j;
    v[j] = (i < n) ? deg[i] : 0;
    sum += v[j];
  }
  int s = sum;
  for (int o = 1; o < 64; o <<= 1) {
    int t = __shfl_up(s, o);
    if (lane >= o) s += t;
  }
  if (lane == 63) wsum[wid] = s;
  __syncthreads();
  if (tid < 16) {
    int w = wsum[tid];
    for (int o = 1; o < 16; o <<= 1) {
      int t = __shfl_up(w, o);
      if (tid >= o) w += t;
    }
    wsum[tid] = w;
  }
  __syncthreads();
  int wbase = (wid > 0) ? wsum[wid - 1] : 0;
  int run = wbase + s - sum;
  for (int j = 0; j < ITEMS; ++j) {
    int i = base + j;
    if (i < n) { off[i] = run; cur[i] = run; run += v[j]; }
  }
  if (tid == 1023) off[n] = run;
}

__global__ __launch_bounds__(1024) void scan_both_kernel(
    int* __restrict__ cur0, int* __restrict__ off0,
    int* __restrict__ cur1, int* __restrict__ off1) {
  if (blockIdx.x == 0) scan_block(cur0, off0, cur0, N1c);
  else                 scan_block(cur1, off1, cur1, Bc);
}

// scatter both graphs; layer-0 sources are map-resolved here
__global__ void scatter_both_kernel(const int* __restrict__ e0, const int* __restrict__ e1,
                                    const int* __restrict__ map,
                                    int* __restrict__ cur0, int* __restrict__ esrc0,
                                    int* __restrict__ cur1, int* __restrict__ esrc1) {
  int i = blockIdx.x * 256 + threadIdx.x;
  if (i < E0c) {
    int p = atomicAdd(&cur0[e0[E0c + i]], 1);
    esrc0[p] = map[e0[i]];
  } else if (i < E0c + E1c) {
    int j = i - E0c;
    int p = atomicAdd(&cur1[e1[E1c + j]], 1);
    esrc1[p] = e1[j];
  }
}

// Conv1 aggregation: one block per dst; 8 slots x 32 lanes, 2 independent row
// streams per slot (16 rows in flight per block), float4 gathers, idx prefetch.
__global__ __launch_bounds__(256) void agg1_kernel(
    const int* __restrict__ off, const int* __restrict__ esrc,
    const float* __restrict__ fc, const float* __restrict__ x,
    float4* __restrict__ mean4) {
  __shared__ float4 sbuf[8][32];
  int d = blockIdx.x;
  int slot = threadIdx.x >> 5, lane = threadIdx.x & 31;
  int s = off[d], e = off[d + 1];
  float4 acc0 = make_float4(0.f, 0.f, 0.f, 0.f);
  float4 acc1 = make_float4(0.f, 0.f, 0.f, 0.f);
  int i0 = s + slot, i1 = s + slot + 8;
  int m0 = (i0 < e) ? esrc[i0] : -1;
  int m1 = (i1 < e) ? esrc[i1] : -1;
  while (i0 < e) {
    int i0n = i0 + 16, i1n = i1 + 16;
    int m0n = (i0n < e) ? esrc[i0n] : -1;   // prefetch next indices
    int m1n = (i1n < e) ? esrc[i1n] : -1;
    const float* r0 = (m0 < C_FEATc) ? (fc + (size_t)m0 * F_INc)
                                     : (x + (size_t)(m0 - C_FEATc) * F_INc);
    float4 v0 = ((const float4*)r0)[lane];
    if (i1 < e) {
      const float* r1 = (m1 < C_FEATc) ? (fc + (size_t)m1 * F_INc)
                                       : (x + (size_t)(m1 - C_FEATc) * F_INc);
      float4 v1 = ((const float4*)r1)[lane];
      acc1.x += v1.x; acc1.y += v1.y; acc1.z += v1.z; acc1.w += v1.w;
    }
    acc0.x += v0.x; acc0.y += v0.y; acc0.z += v0.z; acc0.w += v0.w;
    i0 = i0n; m0 = m0n; i1 = i1n; m1 = m1n;
  }
  acc0.x += acc1.x; acc0.y += acc1.y; acc0.z += acc1.z; acc0.w += acc1.w;
  sbuf[slot][lane] = acc0;
  __syncthreads();
  if (slot < 4) {
    float4 o = sbuf[slot + 4][lane];
    acc0.x += o.x; acc0.y += o.y; acc0.z += o.z; acc0.w += o.w;
    sbuf[slot][lane] = acc0;
  }
  __syncthreads();
  if (slot < 2) {
    float4 o = sbuf[slot + 2][lane];
    acc0.x += o.x; acc0.y += o.y; acc0.z += o.z; acc0.w += o.w;
    sbuf[slot][lane] = acc0;
  }
  __syncthreads();
  if (slot == 0) {
    float4 o = sbuf[1][lane];
    acc0.x += o.x; acc0.y += o.y; acc0.z += o.z; acc0.w += o.w;
    float inv = 1.f / fmaxf((float)(e - s), 1.f);
    mean4[(size_t)d * 32 + lane] = make_float4(acc0.x * inv, acc0.y * inv,
                                               acc0.z * inv, acc0.w * inv);
  }
}

// h1 = relu(mean @ W0l + b0 + hdst @ W0r)   (N1 x 256)
#define ROWS1 16
__global__ __launch_bounds__(256) void gemm1_kernel(
    const float4* __restrict__ mean4, const int* __restrict__ map,
    const float* __restrict__ fc, const float* __restrict__ x,
    const float* __restrict__ W0l, const float* __restrict__ b0,
    const float* __restrict__ W0r, float* __restrict__ h1) {
  __shared__ float lin[ROWS1][256];
  int g0 = blockIdx.x * ROWS1;
  int tid = threadIdx.x;
  for (int idx = tid; idx < ROWS1 * 32; idx += 256) {
    int r = idx >> 5, l = idx & 31;
    ((float4*)&lin[r][0])[l] = mean4[(size_t)(g0 + r) * 32 + l];
  }
  for (int idx = tid; idx < ROWS1 * 32; idx += 256) {
    int r = idx >> 5, l = idx & 31;
    int m = map[g0 + r];
    const float* row = (m < C_FEATc) ? (fc + (size_t)m * F_INc)
                                     : (x + (size_t)(m - C_FEATc) * F_INc);
    ((float4*)&lin[r][128])[l] = ((const float4*)row)[l];
  }
  __syncthreads();
  int col = tid;
  float acc[ROWS1];
#pragma unroll
  for (int r = 0; r < ROWS1; ++r) acc[r] = 0.f;
  for (int kb = 0; kb < 32; ++kb) {
    float w0 = W0l[(kb * 4 + 0) * 256 + col];
    float w1 = W0l[(kb * 4 + 1) * 256 + col];
    float w2 = W0l[(kb * 4 + 2) * 256 + col];
    float w3 = W0l[(kb * 4 + 3) * 256 + col];
#pragma unroll
    for (int r = 0; r < ROWS1; ++r) {
      float4 a = *(const float4*)&lin[r][kb * 4];
      acc[r] += a.x * w0 + a.y * w1 + a.z * w2 + a.w * w3;
    }
  }
  for (int kb = 0; kb < 32; ++kb) {
    float w0 = W0r[(kb * 4 + 0) * 256 + col];
    float w1 = W0r[(kb * 4 + 1) * 256 + col];
    float w2 = W0r[(kb * 4 + 2) * 256 + col];
    float w3 = W0r[(kb * 4 + 3) * 256 + col];
#pragma unroll
    for (int r = 0; r < ROWS1; ++r) {
      float4 a = *(const float4*)&lin[r][128 + kb * 4];
      acc[r] += a.x * w0 + a.y * w1 + a.z * w2 + a.w * w3;
    }
  }
  float b = b0[col];
#pragma unroll
  for (int r = 0; r < ROWS1; ++r) {
    float v = acc[r] + b;
    h1[(size_t)(g0 + r) * HIDc + col] = v > 0.f ? v : 0.f;
  }
}

// push winners (last-wins per cache slot) + pull winners (last-wins per batch row)
__global__ void win_both_kernel(const int* __restrict__ push_gid, const int* __restrict__ table,
                                int* __restrict__ win,
                                const int* __restrict__ pull_bid, int* __restrict__ pwin) {
  int i = blockIdx.x * 256 + threadIdx.x;
  if (i < Pc) atomicMax(&win[table[push_gid[i]]], i);
  else if (i < 2 * Pc) {
    int j = i - Pc;
    atomicMax(&pwin[pull_bid[j]], j);
  }
}

// resolve winning pulls into a row indirection: src_row[b] = h1 row (<N1) or
// N1 + emb_cache row. h1 itself is never mutated -> no snapshot hazard.
__global__ void resolve_kernel(const int* __restrict__ pull_bid, const int* __restrict__ pull_gid,
                               const int* __restrict__ table, const int* __restrict__ win,
                               const int* __restrict__ pwin, const int* __restrict__ push_bid,
                               int* __restrict__ src_row) {
  int i = blockIdx.x * 256 + threadIdx.x;
  if (i >= Pc) return;
  int b = pull_bid[i];
  if (pwin[b] != i) return;
  int slot = table[pull_gid[i]];
  int j = win[slot];
  src_row[b] = (j >= 0) ? push_bid[j] : (N1c + slot);
}

// Fused conv2: mean-agg (through src_row indirection) + GEMM + log_softmax.
__global__ __launch_bounds__(256) void conv2_kernel(
    const int* __restrict__ off, const int* __restrict__ esrc,
    const int* __restrict__ src_row,
    const float* __restrict__ h1, const float* __restrict__ emb,
    const float* __restrict__ W1l, const float* __restrict__ b1,
    const float* __restrict__ W1r, float* __restrict__ out) {
  __shared__ float lin[512];
  __shared__ float partial[64][4];
  int row = blockIdx.x;
  int t = threadIdx.x;
  int s = off[row], e = off[row + 1];
  float acc = 0.f;
  for (int i = s; i < e; ++i) {
    int m = src_row[esrc[i]];
    const float* rp = (m < N1c) ? (h1 + (size_t)m * HIDc)
                                : (emb + (size_t)(m - N1c) * HIDc);
    acc += rp[t];
  }
  lin[t] = acc / fmaxf((float)(e - s), 1.f);
  {
    int m = src_row[row];
    const float* rp = (m < N1c) ? (h1 + (size_t)m * HIDc)
                                : (emb + (size_t)(m - N1c) * HIDc);
    lin[256 + t] = rp[t];
  }
  __syncthreads();
  int col = t >> 2;
  int seg = t & 3;
  float p = 0.f;
  if (col < OUTc) {
    int k0 = seg * 64;
    for (int k = k0; k < k0 + 64; ++k) p += lin[k] * W1l[k * OUTc + col];
    for (int k = k0; k < k0 + 64; ++k) p += lin[256 + k] * W1r[k * OUTc + col];
  }
  partial[col][seg] = p;
  __syncthreads();
  if (t < 64) {
    float v = partial[t][0] + partial[t][1] + partial[t][2] + partial[t][3];
    if (t < OUTc) v += b1[t];
    float vv = (t < OUTc) ? v : -INFINITY;
    float m = vv;
    for (int o = 32; o > 0; o >>= 1) m = fmaxf(m, __shfl_xor(m, o));
    float ex = (t < OUTc) ? expf(vv - m) : 0.f;
    float sum = ex;
    for (int o = 32; o > 0; o >>= 1) sum += __shfl_xor(sum, o);
    if (t < OUTc) out[(size_t)row * OUTc + t] = vv - m - logf(sum);
  }
}

// ---------------------------------------------------------------------------
extern "C" void kernel_launch(void* const* d_in, const int* in_sizes, int n_in,
                              void* d_out, int out_size, void* d_ws, size_t ws_size,
                              hipStream_t stream) {
  const float* x          = (const float*)d_in[0];
  const float* feat_cache = (const float*)d_in[1];
  const float* emb_cache  = (const float*)d_in[2];
  const int* hit_idx      = (const int*)d_in[3];
  const int* hit_pos      = (const int*)d_in[4];
  const int* miss_pos     = (const int*)d_in[5];
  const int* e0           = (const int*)d_in[6];
  const int* e1           = (const int*)d_in[7];
  const int* table        = (const int*)d_in[8];
  const int* push_bid     = (const int*)d_in[9];
  const int* push_gid     = (const int*)d_in[10];
  const int* pull_bid     = (const int*)d_in[11];
  const int* pull_gid     = (const int*)d_in[12];
  const float* W0l        = (const float*)d_in[13];
  const float* b0         = (const float*)d_in[14];
  const float* W0r        = (const float*)d_in[15];
  const float* W1l        = (const float*)d_in[16];
  const float* b1         = (const float*)d_in[17];
  const float* W1r        = (const float*)d_in[18];
  float* out = (float*)d_out;

  char* p = (char*)d_ws;
  size_t ob = 0;
  auto take = [&](size_t bytes) -> void* {
    void* r = p + ob;
    ob += (bytes + 255) & ~(size_t)255;
    return r;
  };
  int* MAP     = (int*)take((size_t)N0c * 4);
  int* OFF0    = (int*)take((size_t)(N1c + 1) * 4);
  int* CUR0    = (int*)take((size_t)N1c * 4);
  int* ESRC0   = (int*)take((size_t)E0c * 4);
  float* MEAN1 = (float*)take((size_t)N1c * F_INc * 4);
  float* H1    = (float*)take((size_t)N1c * HIDc * 4);
  int* WIN     = (int*)take((size_t)N_CACHEc * 4);
  int* PWIN    = (int*)take((size_t)N1c * 4);
  int* SRCROW  = (int*)take((size_t)N1c * 4);
  int* OFF1    = (int*)take((size_t)(Bc + 1) * 4);
  int* CUR1    = (int*)take((size_t)Bc * 4);
  int* ESRC1   = (int*)take((size_t)E1c * 4);

  // 1. map + scratch init
  prep_kernel<<<(H_HITc + 255) / 256, 256, 0, stream>>>(hit_pos, hit_idx, miss_pos,
                                                        MAP, CUR0, PWIN, CUR1, WIN, SRCROW);
  // 2. degrees (both graphs)
  deg_both_kernel<<<(E0c + E1c + 255) / 256, 256, 0, stream>>>(e0, e1, CUR0, CUR1);
  // 3. scans (both graphs)
  scan_both_kernel<<<2, 1024, 0, stream>>>(CUR0, OFF0, CUR1, OFF1);
  // 4. scatter (both graphs)
  scatter_both_kernel<<<(E0c + E1c + 255) / 256, 256, 0, stream>>>(e0, e1, MAP,
                                                                  CUR0, ESRC0, CUR1, ESRC1);
  // 5. conv1 aggregation
  agg1_kernel<<<N1c, 256, 0, stream>>>(OFF0, ESRC0, feat_cache, x, (float4*)MEAN1);
  // 6. conv1 GEMM + relu
  gemm1_kernel<<<N1c / ROWS1, 256, 0, stream>>>((const float4*)MEAN1, MAP, feat_cache, x,
                                                W0l, b0, W0r, H1);
  // 7. push/pull winners
  win_both_kernel<<<(2 * Pc + 255) / 256, 256, 0, stream>>>(push_gid, table, WIN, pull_bid, PWIN);
  // 8. resolve pull indirection
  resolve_kernel<<<(Pc + 255) / 256, 256, 0, stream>>>(pull_bid, pull_gid, table, WIN,
                                                       PWIN, push_bid, SRCROW);
  // 9. conv2 + log_softmax (fused, reads through src_row)
  conv2_kernel<<<Bc, 256, 0, stream>>>(OFF1, ESRC1, SRCROW, H1, emb_cache, W1l, b1, W1r, out);
}

// Round 7
// 350.450 us; speedup vs baseline: 1.3233x; 1.0100x over previous
//
#include <hip/hip_runtime.h>
#include <math.h>

// Problem constants (from reference)
#define N0c     292864
#define N1c     11264
#define Bc      1024
#define F_INc   128
#define HIDc    256
#define OUTc    47
#define E0c     281600
#define E1c     10240
#define H_HITc  146432
#define N_CACHEc 50000
#define C_FEATc 200000
#define Pc      2048

// ---------------------------------------------------------------------------
// prep: build map (h indirection) + init all scratch
__global__ void prep_kernel(const int* __restrict__ hit_pos, const int* __restrict__ hit_idx,
                            const int* __restrict__ miss_pos, int* __restrict__ map,
                            int* __restrict__ cur0, int* __restrict__ pwin,
                            int* __restrict__ cur1, int* __restrict__ win,
                            int* __restrict__ src_row) {
  int i = blockIdx.x * 256 + threadIdx.x;
  if (i < H_HITc) {
    map[hit_pos[i]]  = hit_idx[i];
    map[miss_pos[i]] = C_FEATc + i;
  }
  if (i < N1c) { cur0[i] = 0; pwin[i] = -1; src_row[i] = i; }
  if (i < Bc)  cur1[i] = 0;
  if (i < N_CACHEc) win[i] = -1;
}

// all input-driven atomics in one dispatch: degrees (both graphs) + push/pull winners
__global__ void atomics_kernel(const int* __restrict__ e0, const int* __restrict__ e1,
                               int* __restrict__ deg0, int* __restrict__ deg1,
                               const int* __restrict__ push_gid, const int* __restrict__ table,
                               int* __restrict__ win,
                               const int* __restrict__ pull_bid, int* __restrict__ pwin) {
  int i = blockIdx.x * 256 + threadIdx.x;
  if (i < E0c) {
    atomicAdd(&deg0[e0[E0c + i]], 1);
  } else if (i < E0c + E1c) {
    int j = i - E0c;
    atomicAdd(&deg1[e1[E1c + j]], 1);
  } else if (i < E0c + E1c + Pc) {
    int j = i - E0c - E1c;
    atomicMax(&win[table[push_gid[j]]], j);
  } else if (i < E0c + E1c + 2 * Pc) {
    int j = i - E0c - E1c - Pc;
    atomicMax(&pwin[pull_bid[j]], j);
  }
}

// block-wide exclusive scan (shfl-based), writes off[0..n] and cur[0..n-1]
__device__ void scan_block(const int* __restrict__ deg, int* __restrict__ off,
                           int* __restrict__ cur, int n) {
  __shared__ int wsum[16];
  int tid = threadIdx.x;
  int lane = tid & 63, wid = tid >> 6;
  int ITEMS = (n + 1023) >> 10;
  int base = tid * ITEMS;
  int v[12];
  int sum = 0;
  for (int j = 0; j < ITEMS; ++j) {
    int i = base + j;
    v[j] = (i < n) ? deg[i] : 0;
    sum += v[j];
  }
  int s = sum;
  for (int o = 1; o < 64; o <<= 1) {
    int t = __shfl_up(s, o);
    if (lane >= o) s += t;
  }
  if (lane == 63) wsum[wid] = s;
  __syncthreads();
  if (tid < 16) {
    int w = wsum[tid];
    for (int o = 1; o < 16; o <<= 1) {
      int t = __shfl_up(w, o);
      if (tid >= o) w += t;
    }
    wsum[tid] = w;
  }
  __syncthreads();
  int wbase = (wid > 0) ? wsum[wid - 1] : 0;
  int run = wbase + s - sum;
  for (int j = 0; j < ITEMS; ++j) {
    int i = base + j;
    if (i < n) { off[i] = run; cur[i] = run; run += v[j]; }
  }
  if (tid == 1023) off[n] = run;
}

__global__ __launch_bounds__(1024) void scan_both_kernel(
    int* __restrict__ cur0, int* __restrict__ off0,
    int* __restrict__ cur1, int* __restrict__ off1) {
  if (blockIdx.x == 0) scan_block(cur0, off0, cur0, N1c);
  else                 scan_block(cur1, off1, cur1, Bc);
}

// scatter both graphs (layer-0 map-resolved) + resolve pull indirection
__global__ void scatter_resolve_kernel(const int* __restrict__ e0, const int* __restrict__ e1,
                                       const int* __restrict__ map,
                                       int* __restrict__ cur0, int* __restrict__ esrc0,
                                       int* __restrict__ cur1, int* __restrict__ esrc1,
                                       const int* __restrict__ pull_bid, const int* __restrict__ pull_gid,
                                       const int* __restrict__ table, const int* __restrict__ win,
                                       const int* __restrict__ pwin, const int* __restrict__ push_bid,
                                       int* __restrict__ src_row) {
  int i = blockIdx.x * 256 + threadIdx.x;
  if (i < E0c) {
    int p = atomicAdd(&cur0[e0[E0c + i]], 1);
    esrc0[p] = map[e0[i]];
  } else if (i < E0c + E1c) {
    int j = i - E0c;
    int p = atomicAdd(&cur1[e1[E1c + j]], 1);
    esrc1[p] = e1[j];
  } else if (i < E0c + E1c + Pc) {
    int j = i - E0c - E1c;
    int b = pull_bid[j];
    if (pwin[b] == j) {
      int slot = table[pull_gid[j]];
      int w = win[slot];
      src_row[b] = (w >= 0) ? push_bid[w] : (N1c + slot);
    }
  }
}

// Conv1 aggregation: one block per dst; 8 slots x 32 lanes, 4 independent row
// streams per slot (32 rows in flight per block), float4 gathers, idx prefetch.
__global__ __launch_bounds__(256) void agg1_kernel(
    const int* __restrict__ off, const int* __restrict__ esrc,
    const float* __restrict__ fc, const float* __restrict__ x,
    float4* __restrict__ mean4) {
  __shared__ float4 sbuf[8][32];
  int d = blockIdx.x;
  int slot = threadIdx.x >> 5, lane = threadIdx.x & 31;
  int s = off[d], e = off[d + 1];
  float4 a0 = make_float4(0.f, 0.f, 0.f, 0.f);
  float4 a1 = a0, a2 = a0, a3 = a0;
  int i0 = s + slot, i1 = i0 + 8, i2 = i0 + 16, i3 = i0 + 24;
  int m0 = (i0 < e) ? esrc[i0] : -1;
  int m1 = (i1 < e) ? esrc[i1] : -1;
  int m2 = (i2 < e) ? esrc[i2] : -1;
  int m3 = (i3 < e) ? esrc[i3] : -1;
  while (i0 < e) {
    int n0 = i0 + 32, n1 = i1 + 32, n2 = i2 + 32, n3 = i3 + 32;
    int p0 = (n0 < e) ? esrc[n0] : -1;   // prefetch next indices
    int p1 = (n1 < e) ? esrc[n1] : -1;
    int p2 = (n2 < e) ? esrc[n2] : -1;
    int p3 = (n3 < e) ? esrc[n3] : -1;
    {
      const float* r = (m0 < C_FEATc) ? (fc + (size_t)m0 * F_INc)
                                      : (x + (size_t)(m0 - C_FEATc) * F_INc);
      float4 v = ((const float4*)r)[lane];
      a0.x += v.x; a0.y += v.y; a0.z += v.z; a0.w += v.w;
    }
    if (i1 < e) {
      const float* r = (m1 < C_FEATc) ? (fc + (size_t)m1 * F_INc)
                                      : (x + (size_t)(m1 - C_FEATc) * F_INc);
      float4 v = ((const float4*)r)[lane];
      a1.x += v.x; a1.y += v.y; a1.z += v.z; a1.w += v.w;
    }
    if (i2 < e) {
      const float* r = (m2 < C_FEATc) ? (fc + (size_t)m2 * F_INc)
                                      : (x + (size_t)(m2 - C_FEATc) * F_INc);
      float4 v = ((const float4*)r)[lane];
      a2.x += v.x; a2.y += v.y; a2.z += v.z; a2.w += v.w;
    }
    if (i3 < e) {
      const float* r = (m3 < C_FEATc) ? (fc + (size_t)m3 * F_INc)
                                      : (x + (size_t)(m3 - C_FEATc) * F_INc);
      float4 v = ((const float4*)r)[lane];
      a3.x += v.x; a3.y += v.y; a3.z += v.z; a3.w += v.w;
    }
    i0 = n0; m0 = p0; i1 = n1; m1 = p1; i2 = n2; m2 = p2; i3 = n3; m3 = p3;
  }
  a0.x += a1.x + a2.x + a3.x;
  a0.y += a1.y + a2.y + a3.y;
  a0.z += a1.z + a2.z + a3.z;
  a0.w += a1.w + a2.w + a3.w;
  sbuf[slot][lane] = a0;
  __syncthreads();
  if (slot < 4) {
    float4 o = sbuf[slot + 4][lane];
    a0.x += o.x; a0.y += o.y; a0.z += o.z; a0.w += o.w;
    sbuf[slot][lane] = a0;
  }
  __syncthreads();
  if (slot < 2) {
    float4 o = sbuf[slot + 2][lane];
    a0.x += o.x; a0.y += o.y; a0.z += o.z; a0.w += o.w;
    sbuf[slot][lane] = a0;
  }
  __syncthreads();
  if (slot == 0) {
    float4 o = sbuf[1][lane];
    a0.x += o.x; a0.y += o.y; a0.z += o.z; a0.w += o.w;
    float inv = 1.f / fmaxf((float)(e - s), 1.f);
    mean4[(size_t)d * 32 + lane] = make_float4(a0.x * inv, a0.y * inv,
                                               a0.z * inv, a0.w * inv);
  }
}

// h1 = relu(mean @ W0l + b0 + hdst @ W0r)   (N1 x 256)
#define ROWS1 16
__global__ __launch_bounds__(256) void gemm1_kernel(
    const float4* __restrict__ mean4, const int* __restrict__ map,
    const float* __restrict__ fc, const float* __restrict__ x,
    const float* __restrict__ W0l, const float* __restrict__ b0,
    const float* __restrict__ W0r, float* __restrict__ h1) {
  __shared__ float lin[ROWS1][256];
  int g0 = blockIdx.x * ROWS1;
  int tid = threadIdx.x;
  for (int idx = tid; idx < ROWS1 * 32; idx += 256) {
    int r = idx >> 5, l = idx & 31;
    ((float4*)&lin[r][0])[l] = mean4[(size_t)(g0 + r) * 32 + l];
  }
  for (int idx = tid; idx < ROWS1 * 32; idx += 256) {
    int r = idx >> 5, l = idx & 31;
    int m = map[g0 + r];
    const float* row = (m < C_FEATc) ? (fc + (size_t)m * F_INc)
                                     : (x + (size_t)(m - C_FEATc) * F_INc);
    ((float4*)&lin[r][128])[l] = ((const float4*)row)[l];
  }
  __syncthreads();
  int col = tid;
  float acc[ROWS1];
#pragma unroll
  for (int r = 0; r < ROWS1; ++r) acc[r] = 0.f;
  for (int kb = 0; kb < 32; ++kb) {
    float w0 = W0l[(kb * 4 + 0) * 256 + col];
    float w1 = W0l[(kb * 4 + 1) * 256 + col];
    float w2 = W0l[(kb * 4 + 2) * 256 + col];
    float w3 = W0l[(kb * 4 + 3) * 256 + col];
#pragma unroll
    for (int r = 0; r < ROWS1; ++r) {
      float4 a = *(const float4*)&lin[r][kb * 4];
      acc[r] += a.x * w0 + a.y * w1 + a.z * w2 + a.w * w3;
    }
  }
  for (int kb = 0; kb < 32; ++kb) {
    float w0 = W0r[(kb * 4 + 0) * 256 + col];
    float w1 = W0r[(kb * 4 + 1) * 256 + col];
    float w2 = W0r[(kb * 4 + 2) * 256 + col];
    float w3 = W0r[(kb * 4 + 3) * 256 + col];
#pragma unroll
    for (int r = 0; r < ROWS1; ++r) {
      float4 a = *(const float4*)&lin[r][128 + kb * 4];
      acc[r] += a.x * w0 + a.y * w1 + a.z * w2 + a.w * w3;
    }
  }
  float b = b0[col];
#pragma unroll
  for (int r = 0; r < ROWS1; ++r) {
    float v = acc[r] + b;
    h1[(size_t)(g0 + r) * HIDc + col] = v > 0.f ? v : 0.f;
  }
}

// Fused conv2: mean-agg (through src_row indirection) + GEMM + log_softmax.
__global__ __launch_bounds__(256) void conv2_kernel(
    const int* __restrict__ off, const int* __restrict__ esrc,
    const int* __restrict__ src_row,
    const float* __restrict__ h1, const float* __restrict__ emb,
    const float* __restrict__ W1l, const float* __restrict__ b1,
    const float* __restrict__ W1r, float* __restrict__ out) {
  __shared__ float lin[512];
  __shared__ float partial[64][4];
  int row = blockIdx.x;
  int t = threadIdx.x;
  int s = off[row], e = off[row + 1];
  float acc = 0.f;
  for (int i = s; i < e; ++i) {
    int m = src_row[esrc[i]];
    const float* rp = (m < N1c) ? (h1 + (size_t)m * HIDc)
                                : (emb + (size_t)(m - N1c) * HIDc);
    acc += rp[t];
  }
  lin[t] = acc / fmaxf((float)(e - s), 1.f);
  {
    int m = src_row[row];
    const float* rp = (m < N1c) ? (h1 + (size_t)m * HIDc)
                                : (emb + (size_t)(m - N1c) * HIDc);
    lin[256 + t] = rp[t];
  }
  __syncthreads();
  int col = t >> 2;
  int seg = t & 3;
  float p = 0.f;
  if (col < OUTc) {
    int k0 = seg * 64;
    for (int k = k0; k < k0 + 64; ++k) p += lin[k] * W1l[k * OUTc + col];
    for (int k = k0; k < k0 + 64; ++k) p += lin[256 + k] * W1r[k * OUTc + col];
  }
  partial[col][seg] = p;
  __syncthreads();
  if (t < 64) {
    float v = partial[t][0] + partial[t][1] + partial[t][2] + partial[t][3];
    if (t < OUTc) v += b1[t];
    float vv = (t < OUTc) ? v : -INFINITY;
    float m = vv;
    for (int o = 32; o > 0; o >>= 1) m = fmaxf(m, __shfl_xor(m, o));
    float ex = (t < OUTc) ? expf(vv - m) : 0.f;
    float sum = ex;
    for (int o = 32; o > 0; o >>= 1) sum += __shfl_xor(sum, o);
    if (t < OUTc) out[(size_t)row * OUTc + t] = vv - m - logf(sum);
  }
}

// ---------------------------------------------------------------------------
extern "C" void kernel_launch(void* const* d_in, const int* in_sizes, int n_in,
                              void* d_out, int out_size, void* d_ws, size_t ws_size,
                              hipStream_t stream) {
  const float* x          = (const float*)d_in[0];
  const float* feat_cache = (const float*)d_in[1];
  const float* emb_cache  = (const float*)d_in[2];
  const int* hit_idx      = (const int*)d_in[3];
  const int* hit_pos      = (const int*)d_in[4];
  const int* miss_pos     = (const int*)d_in[5];
  const int* e0           = (const int*)d_in[6];
  const int* e1           = (const int*)d_in[7];
  const int* table        = (const int*)d_in[8];
  const int* push_bid     = (const int*)d_in[9];
  const int* push_gid     = (const int*)d_in[10];
  const int* pull_bid     = (const int*)d_in[11];
  const int* pull_gid     = (const int*)d_in[12];
  const float* W0l        = (const float*)d_in[13];
  const float* b0         = (const float*)d_in[14];
  const float* W0r        = (const float*)d_in[15];
  const float* W1l        = (const float*)d_in[16];
  const float* b1         = (const float*)d_in[17];
  const float* W1r        = (const float*)d_in[18];
  float* out = (float*)d_out;

  char* p = (char*)d_ws;
  size_t ob = 0;
  auto take = [&](size_t bytes) -> void* {
    void* r = p + ob;
    ob += (bytes + 255) & ~(size_t)255;
    return r;
  };
  int* MAP     = (int*)take((size_t)N0c * 4);
  int* OFF0    = (int*)take((size_t)(N1c + 1) * 4);
  int* CUR0    = (int*)take((size_t)N1c * 4);
  int* ESRC0   = (int*)take((size_t)E0c * 4);
  float* MEAN1 = (float*)take((size_t)N1c * F_INc * 4);
  float* H1    = (float*)take((size_t)N1c * HIDc * 4);
  int* WIN     = (int*)take((size_t)N_CACHEc * 4);
  int* PWIN    = (int*)take((size_t)N1c * 4);
  int* SRCROW  = (int*)take((size_t)N1c * 4);
  int* OFF1    = (int*)take((size_t)(Bc + 1) * 4);
  int* CUR1    = (int*)take((size_t)Bc * 4);
  int* ESRC1   = (int*)take((size_t)E1c * 4);

  // 1. map + scratch init
  prep_kernel<<<(H_HITc + 255) / 256, 256, 0, stream>>>(hit_pos, hit_idx, miss_pos,
                                                        MAP, CUR0, PWIN, CUR1, WIN, SRCROW);
  // 2. all atomics: degrees + push/pull winners
  atomics_kernel<<<(E0c + E1c + 2 * Pc + 255) / 256, 256, 0, stream>>>(
      e0, e1, CUR0, CUR1, push_gid, table, WIN, pull_bid, PWIN);
  // 3. scans (both graphs)
  scan_both_kernel<<<2, 1024, 0, stream>>>(CUR0, OFF0, CUR1, OFF1);
  // 4. scatter (both graphs) + resolve pull indirection
  scatter_resolve_kernel<<<(E0c + E1c + Pc + 255) / 256, 256, 0, stream>>>(
      e0, e1, MAP, CUR0, ESRC0, CUR1, ESRC1,
      pull_bid, pull_gid, table, WIN, PWIN, push_bid, SRCROW);
  // 5. conv1 aggregation
  agg1_kernel<<<N1c, 256, 0, stream>>>(OFF0, ESRC0, feat_cache, x, (float4*)MEAN1);
  // 6. conv1 GEMM + relu
  gemm1_kernel<<<N1c / ROWS1, 256, 0, stream>>>((const float4*)MEAN1, MAP, feat_cache, x,
                                                W0l, b0, W0r, H1);
  // 7. conv2 + log_softmax (fused, reads through src_row)
  conv2_kernel<<<Bc, 256, 0, stream>>>(OFF1, ESRC1, SRCROW, H1, emb_cache, W1l, b1, W1r, out);
}

// Round 9
// 323.571 us; speedup vs baseline: 1.4333x; 1.0831x over previous
//
#include <hip/hip_runtime.h>
#include <hip/hip_bf16.h>
#include <math.h>

// Problem constants (from reference)
#define N0c     292864
#define N1c     11264
#define Bc      1024
#define F_INc   128
#define HIDc    256
#define OUTc    47
#define E0c     281600
#define E1c     10240
#define H_HITc  146432
#define N_CACHEc 50000
#define C_FEATc 200000
#define Pc      2048

typedef __attribute__((ext_vector_type(8))) short short8v;   // 8 bf16 = 4 VGPR
typedef __attribute__((ext_vector_type(4))) float f32x4;

__device__ __forceinline__ short f2bf(float f) {
  __hip_bfloat16 h = __float2bfloat16(f);   // RNE
  return *reinterpret_cast<short*>(&h);
}

// ---------------------------------------------------------------------------
// prep: build map + init scratch + build Wt[col][k] bf16 (transposed concat W0l|W0r)
__global__ void prep_kernel(const int* __restrict__ hit_pos, const int* __restrict__ hit_idx,
                            const int* __restrict__ miss_pos, int* __restrict__ map,
                            int* __restrict__ cur0, int* __restrict__ pwin,
                            int* __restrict__ cur1, int* __restrict__ win,
                            int* __restrict__ src_row,
                            const float* __restrict__ W0l, const float* __restrict__ W0r,
                            short* __restrict__ wt) {
  int i = blockIdx.x * 256 + threadIdx.x;
  if (i < H_HITc) {
    map[hit_pos[i]]  = hit_idx[i];
    map[miss_pos[i]] = C_FEATc + i;
  }
  if (i < N1c) { cur0[i] = 0; pwin[i] = -1; src_row[i] = i; }
  if (i < Bc)  cur1[i] = 0;
  if (i < N_CACHEc) win[i] = -1;
  if (i < 32768) {                       // 256 cols x 128 k-pairs
    int col = i & 255, k = (i >> 8) * 2; // k, k+1 on same side of the 128 split
    float v0 = (k < 128) ? W0l[k * 256 + col] : W0r[(k - 128) * 256 + col];
    float v1 = (k + 1 < 128) ? W0l[(k + 1) * 256 + col] : W0r[(k - 127) * 256 + col];
    short2 pk; pk.x = f2bf(v0); pk.y = f2bf(v1);
    *reinterpret_cast<short2*>(&wt[(size_t)col * 256 + k]) = pk;
  }
}

// all input-driven atomics in one dispatch: degrees (both graphs) + push/pull winners
__global__ void atomics_kernel(const int* __restrict__ e0, const int* __restrict__ e1,
                               int* __restrict__ deg0, int* __restrict__ deg1,
                               const int* __restrict__ push_gid, const int* __restrict__ table,
                               int* __restrict__ win,
                               const int* __restrict__ pull_bid, int* __restrict__ pwin) {
  int i = blockIdx.x * 256 + threadIdx.x;
  if (i < E0c) {
    atomicAdd(&deg0[e0[E0c + i]], 1);
  } else if (i < E0c + E1c) {
    int j = i - E0c;
    atomicAdd(&deg1[e1[E1c + j]], 1);
  } else if (i < E0c + E1c + Pc) {
    int j = i - E0c - E1c;
    atomicMax(&win[table[push_gid[j]]], j);
  } else if (i < E0c + E1c + 2 * Pc) {
    int j = i - E0c - E1c - Pc;
    atomicMax(&pwin[pull_bid[j]], j);
  }
}

// block-wide exclusive scan (shfl-based), writes off[0..n] and cur[0..n-1]
__device__ void scan_block(const int* __restrict__ deg, int* __restrict__ off,
                           int* __restrict__ cur, int n) {
  __shared__ int wsum[16];
  int tid = threadIdx.x;
  int lane = tid & 63, wid = tid >> 6;
  int ITEMS = (n + 1023) >> 10;
  int base = tid * ITEMS;
  int v[12];
  int sum = 0;
  for (int j = 0; j < ITEMS; ++j) {
    int i = base + j;
    v[j] = (i < n) ? deg[i] : 0;
    sum += v[j];
  }
  int s = sum;
  for (int o = 1; o < 64; o <<= 1) {
    int t = __shfl_up(s, o);
    if (lane >= o) s += t;
  }
  if (lane == 63) wsum[wid] = s;
  __syncthreads();
  if (tid < 16) {
    int w = wsum[tid];
    for (int o = 1; o < 16; o <<= 1) {
      int t = __shfl_up(w, o);
      if (tid >= o) w += t;
    }
    wsum[tid] = w;
  }
  __syncthreads();
  int wbase = (wid > 0) ? wsum[wid - 1] : 0;
  int run = wbase + s - sum;
  for (int j = 0; j < ITEMS; ++j) {
    int i = base + j;
    if (i < n) { off[i] = run; cur[i] = run; run += v[j]; }
  }
  if (tid == 1023) off[n] = run;
}

__global__ __launch_bounds__(1024) void scan_both_kernel(
    int* __restrict__ cur0, int* __restrict__ off0,
    int* __restrict__ cur1, int* __restrict__ off1) {
  if (blockIdx.x == 0) scan_block(cur0, off0, cur0, N1c);
  else                 scan_block(cur1, off1, cur1, Bc);
}

// scatter both graphs (layer-0 map-resolved) + resolve pull indirection
__global__ void scatter_resolve_kernel(const int* __restrict__ e0, const int* __restrict__ e1,
                                       const int* __restrict__ map,
                                       int* __restrict__ cur0, int* __restrict__ esrc0,
                                       int* __restrict__ cur1, int* __restrict__ esrc1,
                                       const int* __restrict__ pull_bid, const int* __restrict__ pull_gid,
                                       const int* __restrict__ table, const int* __restrict__ win,
                                       const int* __restrict__ pwin, const int* __restrict__ push_bid,
                                       int* __restrict__ src_row) {
  int i = blockIdx.x * 256 + threadIdx.x;
  if (i < E0c) {
    int p = atomicAdd(&cur0[e0[E0c + i]], 1);
    esrc0[p] = map[e0[i]];
  } else if (i < E0c + E1c) {
    int j = i - E0c;
    int p = atomicAdd(&cur1[e1[E1c + j]], 1);
    esrc1[p] = e1[j];
  } else if (i < E0c + E1c + Pc) {
    int j = i - E0c - E1c;
    int b = pull_bid[j];
    if (pwin[b] == j) {
      int slot = table[pull_gid[j]];
      int w = win[slot];
      src_row[b] = (w >= 0) ? push_bid[w] : (N1c + slot);
    }
  }
}

// Conv1 aggregation: one block per dst; 8 slots x 32 lanes, 4 independent row
// streams per slot (32 rows in flight per block), float4 gathers, idx prefetch.
__global__ __launch_bounds__(256) void agg1_kernel(
    const int* __restrict__ off, const int* __restrict__ esrc,
    const float* __restrict__ fc, const float* __restrict__ x,
    float4* __restrict__ mean4) {
  __shared__ float4 sbuf[8][32];
  int d = blockIdx.x;
  int slot = threadIdx.x >> 5, lane = threadIdx.x & 31;
  int s = off[d], e = off[d + 1];
  float4 a0 = make_float4(0.f, 0.f, 0.f, 0.f);
  float4 a1 = a0, a2 = a0, a3 = a0;
  int i0 = s + slot, i1 = i0 + 8, i2 = i0 + 16, i3 = i0 + 24;
  int m0 = (i0 < e) ? esrc[i0] : -1;
  int m1 = (i1 < e) ? esrc[i1] : -1;
  int m2 = (i2 < e) ? esrc[i2] : -1;
  int m3 = (i3 < e) ? esrc[i3] : -1;
  while (i0 < e) {
    int n0 = i0 + 32, n1 = i1 + 32, n2 = i2 + 32, n3 = i3 + 32;
    int p0 = (n0 < e) ? esrc[n0] : -1;   // prefetch next indices
    int p1 = (n1 < e) ? esrc[n1] : -1;
    int p2 = (n2 < e) ? esrc[n2] : -1;
    int p3 = (n3 < e) ? esrc[n3] : -1;
    {
      const float* r = (m0 < C_FEATc) ? (fc + (size_t)m0 * F_INc)
                                      : (x + (size_t)(m0 - C_FEATc) * F_INc);
      float4 v = ((const float4*)r)[lane];
      a0.x += v.x; a0.y += v.y; a0.z += v.z; a0.w += v.w;
    }
    if (i1 < e) {
      const float* r = (m1 < C_FEATc) ? (fc + (size_t)m1 * F_INc)
                                      : (x + (size_t)(m1 - C_FEATc) * F_INc);
      float4 v = ((const float4*)r)[lane];
      a1.x += v.x; a1.y += v.y; a1.z += v.z; a1.w += v.w;
    }
    if (i2 < e) {
      const float* r = (m2 < C_FEATc) ? (fc + (size_t)m2 * F_INc)
                                      : (x + (size_t)(m2 - C_FEATc) * F_INc);
      float4 v = ((const float4*)r)[lane];
      a2.x += v.x; a2.y += v.y; a2.z += v.z; a2.w += v.w;
    }
    if (i3 < e) {
      const float* r = (m3 < C_FEATc) ? (fc + (size_t)m3 * F_INc)
                                      : (x + (size_t)(m3 - C_FEATc) * F_INc);
      float4 v = ((const float4*)r)[lane];
      a3.x += v.x; a3.y += v.y; a3.z += v.z; a3.w += v.w;
    }
    i0 = n0; m0 = p0; i1 = n1; m1 = p1; i2 = n2; m2 = p2; i3 = n3; m3 = p3;
  }
  a0.x += a1.x + a2.x + a3.x;
  a0.y += a1.y + a2.y + a3.y;
  a0.z += a1.z + a2.z + a3.z;
  a0.w += a1.w + a2.w + a3.w;
  sbuf[slot][lane] = a0;
  __syncthreads();
  if (slot < 4) {
    float4 o = sbuf[slot + 4][lane];
    a0.x += o.x; a0.y += o.y; a0.z += o.z; a0.w += o.w;
    sbuf[slot][lane] = a0;
  }
  __syncthreads();
  if (slot < 2) {
    float4 o = sbuf[slot + 2][lane];
    a0.x += o.x; a0.y += o.y; a0.z += o.z; a0.w += o.w;
    sbuf[slot][lane] = a0;
  }
  __syncthreads();
  if (slot == 0) {
    float4 o = sbuf[1][lane];
    a0.x += o.x; a0.y += o.y; a0.z += o.z; a0.w += o.w;
    float inv = 1.f / fmaxf((float)(e - s), 1.f);
    mean4[(size_t)d * 32 + lane] = make_float4(a0.x * inv, a0.y * inv,
                                               a0.z * inv, a0.w * inv);
  }
}

// h1 = relu([mean|hdst](bf16) @ Wt^T(bf16) + b0) via 16x16x32 bf16 MFMA, f32 accum.
// Block: 16 rows, 4 waves; wave w owns cols [w*64, w*64+64). K = 256 (concat).
// A frag: row = lane&15, k = ks*32 + (lane>>4)*8 + j  (ds_read_b128 from padded LDS)
// B frag: col = lane&15 (+nb*16+col0), same k range    (16B global from Wt[col][k])
// C frag: col = lane&15, row = (lane>>4)*4 + reg       [verified layout]
__global__ __launch_bounds__(256) void gemm1_mfma_kernel(
    const float4* __restrict__ mean4, const int* __restrict__ map,
    const float* __restrict__ fc, const float* __restrict__ x,
    const short* __restrict__ wt, const float* __restrict__ b0,
    float* __restrict__ h1) {
  __shared__ short Abf[16][264];   // +8 bf16 pad -> bank-friendly (2-way, free)
  int g0 = blockIdx.x * 16;
  int tid = threadIdx.x;
  // stage mean rows (f32 -> bf16)
  for (int idx = tid; idx < 512; idx += 256) {
    int r = idx >> 5, l = idx & 31;
    float4 v = mean4[(size_t)(g0 + r) * 32 + l];
    short4 pk; pk.x = f2bf(v.x); pk.y = f2bf(v.y); pk.z = f2bf(v.z); pk.w = f2bf(v.w);
    *reinterpret_cast<short4*>(&Abf[r][l * 4]) = pk;
  }
  // stage hdst rows (gather, f32 -> bf16)
  for (int idx = tid; idx < 512; idx += 256) {
    int r = idx >> 5, l = idx & 31;
    int m = map[g0 + r];
    const float* row = (m < C_FEATc) ? (fc + (size_t)m * F_INc)
                                     : (x + (size_t)(m - C_FEATc) * F_INc);
    float4 v = ((const float4*)row)[l];
    short4 pk; pk.x = f2bf(v.x); pk.y = f2bf(v.y); pk.z = f2bf(v.z); pk.w = f2bf(v.w);
    *reinterpret_cast<short4*>(&Abf[r][128 + l * 4]) = pk;
  }
  __syncthreads();
  int wave = tid >> 6, lane = tid & 63;
  int col0 = wave * 64;
  int lr = lane & 15;          // A row / B,C col selector
  int kg = lane >> 4;          // k-group 0..3
  f32x4 acc0 = {0.f, 0.f, 0.f, 0.f};
  f32x4 acc1 = acc0, acc2 = acc0, acc3 = acc0;
#pragma unroll
  for (int ks = 0; ks < 8; ++ks) {
    int k0 = ks * 32 + kg * 8;
    short8v a = *reinterpret_cast<const short8v*>(&Abf[lr][k0]);
    short8v bv0 = *reinterpret_cast<const short8v*>(&wt[(size_t)(col0 + 0  + lr) * 256 + k0]);
    short8v bv1 = *reinterpret_cast<const short8v*>(&wt[(size_t)(col0 + 16 + lr) * 256 + k0]);
    short8v bv2 = *reinterpret_cast<const short8v*>(&wt[(size_t)(col0 + 32 + lr) * 256 + k0]);
    short8v bv3 = *reinterpret_cast<const short8v*>(&wt[(size_t)(col0 + 48 + lr) * 256 + k0]);
    acc0 = __builtin_amdgcn_mfma_f32_16x16x32_bf16(a, bv0, acc0, 0, 0, 0);
    acc1 = __builtin_amdgcn_mfma_f32_16x16x32_bf16(a, bv1, acc1, 0, 0, 0);
    acc2 = __builtin_amdgcn_mfma_f32_16x16x32_bf16(a, bv2, acc2, 0, 0, 0);
    acc3 = __builtin_amdgcn_mfma_f32_16x16x32_bf16(a, bv3, acc3, 0, 0, 0);
  }
  int rbase = kg * 4;
#pragma unroll
  for (int nb = 0; nb < 4; ++nb) {
    f32x4 acc = (nb == 0) ? acc0 : (nb == 1) ? acc1 : (nb == 2) ? acc2 : acc3;
    int col = col0 + nb * 16 + lr;
    float bias = b0[col];
#pragma unroll
    for (int r = 0; r < 4; ++r) {
      float v = acc[r] + bias;
      h1[(size_t)(g0 + rbase + r) * HIDc + col] = v > 0.f ? v : 0.f;
    }
  }
}

// Fused conv2: mean-agg (through src_row indirection) + GEMM + log_softmax.
__global__ __launch_bounds__(256) void conv2_kernel(
    const int* __restrict__ off, const int* __restrict__ esrc,
    const int* __restrict__ src_row,
    const float* __restrict__ h1, const float* __restrict__ emb,
    const float* __restrict__ W1l, const float* __restrict__ b1,
    const float* __restrict__ W1r, float* __restrict__ out) {
  __shared__ float lin[512];
  __shared__ float partial[64][4];
  int row = blockIdx.x;
  int t = threadIdx.x;
  int s = off[row], e = off[row + 1];
  float acc = 0.f;
  for (int i = s; i < e; ++i) {
    int m = src_row[esrc[i]];
    const float* rp = (m < N1c) ? (h1 + (size_t)m * HIDc)
                                : (emb + (size_t)(m - N1c) * HIDc);
    acc += rp[t];
  }
  lin[t] = acc / fmaxf((float)(e - s), 1.f);
  {
    int m = src_row[row];
    const float* rp = (m < N1c) ? (h1 + (size_t)m * HIDc)
                                : (emb + (size_t)(m - N1c) * HIDc);
    lin[256 + t] = rp[t];
  }
  __syncthreads();
  int col = t >> 2;
  int seg = t & 3;
  float p = 0.f;
  if (col < OUTc) {
    int k0 = seg * 64;
    for (int k = k0; k < k0 + 64; ++k) p += lin[k] * W1l[k * OUTc + col];
    for (int k = k0; k < k0 + 64; ++k) p += lin[256 + k] * W1r[k * OUTc + col];
  }
  partial[col][seg] = p;
  __syncthreads();
  if (t < 64) {
    float v = partial[t][0] + partial[t][1] + partial[t][2] + partial[t][3];
    if (t < OUTc) v += b1[t];
    float vv = (t < OUTc) ? v : -INFINITY;
    float m = vv;
    for (int o = 32; o > 0; o >>= 1) m = fmaxf(m, __shfl_xor(m, o));
    float ex = (t < OUTc) ? expf(vv - m) : 0.f;
    float sum = ex;
    for (int o = 32; o > 0; o >>= 1) sum += __shfl_xor(sum, o);
    if (t < OUTc) out[(size_t)row * OUTc + t] = vv - m - logf(sum);
  }
}

// ---------------------------------------------------------------------------
extern "C" void kernel_launch(void* const* d_in, const int* in_sizes, int n_in,
                              void* d_out, int out_size, void* d_ws, size_t ws_size,
                              hipStream_t stream) {
  const float* x          = (const float*)d_in[0];
  const float* feat_cache = (const float*)d_in[1];
  const float* emb_cache  = (const float*)d_in[2];
  const int* hit_idx      = (const int*)d_in[3];
  const int* hit_pos      = (const int*)d_in[4];
  const int* miss_pos     = (const int*)d_in[5];
  const int* e0           = (const int*)d_in[6];
  const int* e1           = (const int*)d_in[7];
  const int* table        = (const int*)d_in[8];
  const int* push_bid     = (const int*)d_in[9];
  const int* push_gid     = (const int*)d_in[10];
  const int* pull_bid     = (const int*)d_in[11];
  const int* pull_gid     = (const int*)d_in[12];
  const float* W0l        = (const float*)d_in[13];
  const float* b0         = (const float*)d_in[14];
  const float* W0r        = (const float*)d_in[15];
  const float* W1l        = (const float*)d_in[16];
  const float* b1         = (const float*)d_in[17];
  const float* W1r        = (const float*)d_in[18];
  float* out = (float*)d_out;

  char* p = (char*)d_ws;
  size_t ob = 0;
  auto take = [&](size_t bytes) -> void* {
    void* r = p + ob;
    ob += (bytes + 255) & ~(size_t)255;
    return r;
  };
  int* MAP     = (int*)take((size_t)N0c * 4);
  int* OFF0    = (int*)take((size_t)(N1c + 1) * 4);
  int* CUR0    = (int*)take((size_t)N1c * 4);
  int* ESRC0   = (int*)take((size_t)E0c * 4);
  float* MEAN1 = (float*)take((size_t)N1c * F_INc * 4);
  float* H1    = (float*)take((size_t)N1c * HIDc * 4);
  int* WIN     = (int*)take((size_t)N_CACHEc * 4);
  int* PWIN    = (int*)take((size_t)N1c * 4);
  int* SRCROW  = (int*)take((size_t)N1c * 4);
  int* OFF1    = (int*)take((size_t)(Bc + 1) * 4);
  int* CUR1    = (int*)take((size_t)Bc * 4);
  int* ESRC1   = (int*)take((size_t)E1c * 4);
  short* WT    = (short*)take((size_t)HIDc * HIDc * 2);   // Wt[col][k] bf16

  // 1. map + scratch init + W transpose/bf16
  prep_kernel<<<(H_HITc + 255) / 256, 256, 0, stream>>>(hit_pos, hit_idx, miss_pos,
                                                        MAP, CUR0, PWIN, CUR1, WIN, SRCROW,
                                                        W0l, W0r, WT);
  // 2. all atomics: degrees + push/pull winners
  atomics_kernel<<<(E0c + E1c + 2 * Pc + 255) / 256, 256, 0, stream>>>(
      e0, e1, CUR0, CUR1, push_gid, table, WIN, pull_bid, PWIN);
  // 3. scans (both graphs)
  scan_both_kernel<<<2, 1024, 0, stream>>>(CUR0, OFF0, CUR1, OFF1);
  // 4. scatter (both graphs) + resolve pull indirection
  scatter_resolve_kernel<<<(E0c + E1c + Pc + 255) / 256, 256, 0, stream>>>(
      e0, e1, MAP, CUR0, ESRC0, CUR1, ESRC1,
      pull_bid, pull_gid, table, WIN, PWIN, push_bid, SRCROW);
  // 5. conv1 aggregation
  agg1_kernel<<<N1c, 256, 0, stream>>>(OFF0, ESRC0, feat_cache, x, (float4*)MEAN1);
  // 6. conv1 GEMM + relu (bf16 MFMA)
  gemm1_mfma_kernel<<<N1c / 16, 256, 0, stream>>>((const float4*)MEAN1, MAP, feat_cache, x,
                                                  WT, b0, H1);
  // 7. conv2 + log_softmax (fused, reads through src_row)
  conv2_kernel<<<Bc, 256, 0, stream>>>(OFF1, ESRC1, SRCROW, H1, emb_cache, W1l, b1, W1r, out);
}